// Round 2
// baseline (1252.977 us; speedup 1.0000x reference)
//
#include <hip/hip_runtime.h>
#include <cmath>

#define NN   1000
#define TT   4
#define PP   10
#define DD   13
#define FF   128
#define HH   128
#define EAA  16
#define KDIM 64
#define EE   20000
#define I_NODE 91
#define I_EDGE 169
#define MROW  13000   // N*D
#define EB   8        // edges per block in k_edge_block
#define NI   (2*EB)   // instances (ij and ji per edge)
#define CHUNKS_PER_TYPE ((EE + EB - 1) / EB)   // 2500

// ---------------- K0: zero the 676MB output (memset is only 1.5 TB/s) -------
__global__ __launch_bounds__(256) void k_zero(float4* __restrict__ p, long n4) {
  long i = (long)blockIdx.x * 256 + threadIdx.x;
  long stride = (long)gridDim.x * 256;
  float4 z = make_float4(0.f, 0.f, 0.f, 0.f);
  for (; i < n4; i += stride) p[i] = z;
}

// ---------------- K1: m = node_feats @ W_msg ; zero agg ----------------
__global__ __launch_bounds__(128) void k_node_msg(
    const float* __restrict__ nf, const float* __restrict__ Wmsg,
    float* __restrict__ m, float* __restrict__ agg) {
  int n = blockIdx.x, j = threadIdx.x;
  __shared__ float row[FF];
  row[j] = nf[n * FF + j];
  __syncthreads();
  float acc = 0.f;
#pragma unroll 8
  for (int f = 0; f < FF; ++f) acc += row[f] * Wmsg[f * FF + j];
  m[n * FF + j] = acc;
  agg[n * FF + j] = 0.f;
}

// ---------------- K2: symmetric segment sum via atomics ----------------
__global__ __launch_bounds__(256) void k_scatter(
    const float* __restrict__ m, const int* __restrict__ src,
    const int* __restrict__ dst, float* __restrict__ agg) {
  int idx = blockIdx.x * 256 + threadIdx.x;
  if (idx >= EE * FF) return;
  int e = idx >> 7, j = idx & 127;
  int s = src[e], d = dst[e];
  atomicAdd(&agg[d * FF + j], m[s * FF + j]);
  atomicAdd(&agg[s * FF + j], m[d * FF + j]);
}

// ---------------- K3: node_h ----------------
__global__ __launch_bounds__(128) void k_node_h(
    const float* __restrict__ nf, const float* __restrict__ agg,
    const float* __restrict__ na, const float* __restrict__ Wattr,
    float* __restrict__ nh) {
  int n = blockIdx.x, j = threadIdx.x;
  float a = 0.f;
#pragma unroll
  for (int t = 0; t < TT; ++t) a += na[n * TT + t] * Wattr[t * FF + j];
  nh[n * FF + j] = nf[n * FF + j] + agg[n * FF + j] * (1.0f / 20.0f) + a;
}

// ---------------- K4: edge_msg = tanh(e_in @ W_em), 8 edges/block ----------------
#define EPB 8
__global__ __launch_bounds__(128) void k_edge_msg(
    const float* __restrict__ nh, const float* __restrict__ ef,
    const float* __restrict__ ea, const int* __restrict__ src,
    const int* __restrict__ dst, const float* __restrict__ Wem,
    float* __restrict__ emsg) {
  int e0 = blockIdx.x * EPB;
  int j = threadIdx.x;
  __shared__ float xin[EPB][2 * FF + 2 * EAA];  // [8][288]
  for (int e = 0; e < EPB; ++e) {
    int ee = e0 + e;
    int s = src[ee], d = dst[ee];
    for (int i = j; i < 288; i += 128) {
      float v;
      if (i < 128)      v = nh[s * FF + i];
      else if (i < 256) v = nh[d * FF + (i - 128)];
      else if (i < 272) v = ef[ee * EAA + (i - 256)];
      else              v = ea[ee * EAA + (i - 272)];
      xin[e][i] = v;
    }
  }
  __syncthreads();
  float acc[EPB];
#pragma unroll
  for (int e = 0; e < EPB; ++e) acc[e] = 0.f;
  for (int i = 0; i < 288; ++i) {
    float w = Wem[i * HH + j];
#pragma unroll
    for (int e = 0; e < EPB; ++e) acc[e] += xin[e][i] * w;
  }
#pragma unroll
  for (int e = 0; e < EPB; ++e) emsg[(e0 + e) * HH + j] = tanhf(acc[e]);
}

// ---------------- K5: node diagonal blocks ----------------
__global__ __launch_bounds__(256) void k_node_block(
    const float* __restrict__ nh, const int* __restrict__ ntype,
    const float* __restrict__ Wnode, const float* __restrict__ cob,
    float* __restrict__ M) {
  int n = blockIdx.x, t = threadIdx.x;
  int ty = ntype[n];
  __shared__ float row[FF];
  __shared__ float irr[I_NODE];
  if (t < FF) row[t] = nh[n * FF + t];
  __syncthreads();
  if (t < I_NODE) {
    float acc = 0.f;
    const float* W = Wnode + ty * FF * I_NODE + t;
#pragma unroll 4
    for (int f = 0; f < FF; ++f) acc += row[f] * W[f * I_NODE];
    irr[t] = acc;
  }
  __syncthreads();
  if (t < I_EDGE) {
    float acc = 0.f;
    const float* C = cob + ty * I_NODE * I_EDGE + t;
    for (int i = 0; i < I_NODE; ++i) acc += irr[i] * C[i * I_EDGE];
    int x = t / DD, y = t % DD;
    atomicAdd(&M[(size_t)(n * DD + x) * MROW + (n * DD + y)], acc);
  }
}

// ---------------- K6a: zero per-type counters ----------------
__global__ void k_zero_counts(int* __restrict__ cnt) {
  if (threadIdx.x < PP) cnt[threadIdx.x] = 0;
}

// ---------------- K6b: bucket edges by type ----------------
__global__ __launch_bounds__(256) void k_bucket(
    const int* __restrict__ etype, int* __restrict__ cnt, int* __restrict__ list) {
  int e = blockIdx.x * 256 + threadIdx.x;
  if (e >= EE) return;
  int p = etype[e];
  int r = atomicAdd(&cnt[p], 1);
  list[p * EE + r] = e;
}

// ---------------- K6c: edge blocks, 8 same-type edges per block --------------
__global__ __launch_bounds__(256) void k_edge_block(
    const float* __restrict__ nh, const float* __restrict__ emsg,
    const int* __restrict__ src, const int* __restrict__ dst,
    const int* __restrict__ cnt, const int* __restrict__ list,
    const float* __restrict__ Wproj, const float* __restrict__ Wedge,
    const float* __restrict__ cob, float* __restrict__ M) {
  int p = blockIdx.x / CHUNKS_PER_TYPE;
  int chunk = blockIdx.x % CHUNKS_PER_TYPE;
  int ecnt = cnt[p];
  int base = chunk * EB;
  if (base >= ecnt) return;            // uniform early exit (most blocks)
  int nval = ecnt - base; if (nval > EB) nval = EB;

  int t = threadIdx.x;
  __shared__ float xin[EB][384];       // [msg(128) | nh_s(128) | nh_d(128)] per edge
  __shared__ float sh_h[NI][KDIM];     // h for ij/ji instances
  __shared__ float sh_irr[NI][I_EDGE];
  __shared__ float sh_blk[NI][I_EDGE];
  __shared__ int se[EB], de[EB], eid[EB];

  if (t < EB) {
    int slot = (t < nval) ? t : 0;     // dup first edge for invalid slots
    int e = list[p * EE + base + slot];
    eid[t] = e; se[t] = src[e]; de[t] = dst[e];
  }
  __syncthreads();

  // stage inputs
  for (int e = 0; e < EB; ++e) {
    int ee = eid[e], s = se[e], d = de[e];
    for (int i = t; i < 384; i += 256) {
      float v;
      if (i < 128)      v = emsg[ee * HH + i];
      else if (i < 256) v = nh[s * FF + (i - 128)];
      else              v = nh[d * FF + (i - 256)];
      xin[e][i] = v;
    }
  }
  __syncthreads();

  // phase 2: h = x @ W_proj  (384x64). group g = t>>6 handles edges {2g, 2g+1},
  // both directions. instance index = edge*2 + dir.
  {
    int k = t & 63, g = t >> 6;
    int e0 = g * 2, e1 = g * 2 + 1;
    float a0 = 0.f, a1 = 0.f, a2 = 0.f, a3 = 0.f;
    const float* Wp = Wproj + k;
    for (int i = 0; i < 384; ++i) {
      float w = Wp[i * KDIM];
      int iswap = (i < 128) ? i : ((i < 256) ? i + 128 : i - 128);
      a0 += xin[e0][i] * w;
      a1 += xin[e0][iswap] * w;
      a2 += xin[e1][i] * w;
      a3 += xin[e1][iswap] * w;
    }
    sh_h[e0 * 2 + 0][k] = a0;
    sh_h[e0 * 2 + 1][k] = a1;
    sh_h[e1 * 2 + 0][k] = a2;
    sh_h[e1 * 2 + 1][k] = a3;
  }
  __syncthreads();

  // phase 3: irr = h @ W_edge[p]  (64x169), 16 instances share each weight
  if (t < I_EDGE) {
    float acc[NI];
#pragma unroll
    for (int q = 0; q < NI; ++q) acc[q] = 0.f;
    const float* W = Wedge + p * KDIM * I_EDGE + t;
#pragma unroll 2
    for (int k = 0; k < KDIM; ++k) {
      float w = W[k * I_EDGE];
#pragma unroll
      for (int q = 0; q < NI; ++q) acc[q] += sh_h[q][k] * w;
    }
#pragma unroll
    for (int q = 0; q < NI; ++q) sh_irr[q][t] = acc[q];
  }
  __syncthreads();

  // phase 4: blk = irr @ cob_edge[p]  (169x169), 16 instances per weight load
  if (t < I_EDGE) {
    float acc[NI];
#pragma unroll
    for (int q = 0; q < NI; ++q) acc[q] = 0.f;
    const float* C = cob + p * I_EDGE * I_EDGE + t;
#pragma unroll 2
    for (int i = 0; i < I_EDGE; ++i) {
      float c = C[i * I_EDGE];
#pragma unroll
      for (int q = 0; q < NI; ++q) acc[q] += sh_irr[q][i] * c;
    }
#pragma unroll
    for (int q = 0; q < NI; ++q) sh_blk[q][t] = acc[q];
  }
  __syncthreads();

  // phase 5: symmetrize + scatter
  if (t < I_EDGE) {
    int x = t / DD, y = t % DD;
    for (int e = 0; e < nval; ++e) {
      int s = se[e], d = de[e];
      float eb = 0.5f * (sh_blk[e * 2 + 0][t] + sh_blk[e * 2 + 1][y * DD + x]);
      atomicAdd(&M[(size_t)(s * DD + x) * MROW + (d * DD + y)], eb);
      atomicAdd(&M[(size_t)(d * DD + y) * MROW + (s * DD + x)], eb);
    }
  }
}

extern "C" void kernel_launch(void* const* d_in, const int* in_sizes, int n_in,
                              void* d_out, int out_size, void* d_ws, size_t ws_size,
                              hipStream_t stream) {
  const float* node_feats = (const float*)d_in[0];
  const float* node_attrs = (const float*)d_in[1];
  const float* edge_feats = (const float*)d_in[2];
  const float* edge_attrs = (const float*)d_in[3];
  const int*   edge_index = (const int*)d_in[4];
  const int*   node_types = (const int*)d_in[5];
  const int*   edge_types = (const int*)d_in[6];
  const float* W_msg  = (const float*)d_in[7];
  const float* W_attr = (const float*)d_in[8];
  const float* W_em   = (const float*)d_in[9];
  const float* W_proj = (const float*)d_in[10];
  const float* W_node = (const float*)d_in[11];
  const float* W_edge = (const float*)d_in[12];
  const float* cob_node = (const float*)d_in[13];
  const float* cob_edge = (const float*)d_in[14];

  float* M  = (float*)d_out;
  float* ws = (float*)d_ws;
  float* m_buf = ws;              // N*F = 128000
  float* agg   = ws + 128000;     // N*F
  float* nh    = ws + 256000;     // N*F
  float* emsg  = ws + 384000;     // E*H = 2,560,000
  int*   cnt   = (int*)(ws + 2944000);    // 10
  int*   list  = cnt + 16;                // P*EE = 200,000  (total ~12.6 MB)

  const int* src = edge_index;        // edge_index[0]
  const int* dst = edge_index + EE;   // edge_index[1]

  long n4 = (long)out_size / 4;       // 169e6 floats / 4 per float4
  k_zero       <<<16384, 256, 0, stream>>>((float4*)M, n4);
  k_zero_counts<<<1, 64, 0, stream>>>(cnt);
  k_bucket     <<<(EE + 255) / 256, 256, 0, stream>>>(edge_types, cnt, list);
  k_node_msg   <<<NN, 128, 0, stream>>>(node_feats, W_msg, m_buf, agg);
  k_scatter    <<<(EE * FF) / 256, 256, 0, stream>>>(m_buf, src, dst, agg);
  k_node_h     <<<NN, 128, 0, stream>>>(node_feats, agg, node_attrs, W_attr, nh);
  k_edge_msg   <<<EE / EPB, 128, 0, stream>>>(nh, edge_feats, edge_attrs, src, dst, W_em, emsg);
  k_node_block <<<NN, 256, 0, stream>>>(nh, node_types, W_node, cob_node, M);
  k_edge_block <<<PP * CHUNKS_PER_TYPE, 256, 0, stream>>>(
      nh, emsg, src, dst, cnt, list, W_proj, W_edge, cob_edge, M);
}

// Round 3
// 919.919 us; speedup vs baseline: 1.3621x; 1.3621x over previous
//
#include <hip/hip_runtime.h>
#include <cmath>

#define NN   1000
#define TT   4
#define PP   10
#define DD   13
#define FF   128
#define HH   128
#define EAA  16
#define KDIM 64
#define EE   20000
#define I_NODE 91
#define I_EDGE 169
#define MROW  13000   // N*D

// ---------------- K0: zero the 676MB output, one float4 store/thread --------
__global__ __launch_bounds__(256) void k_zero(float4* __restrict__ p, long n4) {
  long i = (long)blockIdx.x * 256 + threadIdx.x;
  if (i < n4) p[i] = make_float4(0.f, 0.f, 0.f, 0.f);
}

// ---------------- Kc1: Wcomb[p] = W_edge[p] @ cob_edge[p]  ([10][64][169]) --
__global__ __launch_bounds__(192) void k_comb_edge(
    const float* __restrict__ We, const float* __restrict__ cob,
    float* __restrict__ Wcomb) {
  int pk = blockIdx.x;            // p*64 + k
  int p = pk >> 6;
  int t = threadIdx.x;
  if (t >= I_EDGE) return;
  float acc = 0.f;
  const float* wrow = We + pk * I_EDGE;              // W_edge[p][k][:]
  const float* crow = cob + p * I_EDGE * I_EDGE + t; // cob[p][:][t]
  for (int i = 0; i < I_EDGE; ++i) acc += wrow[i] * crow[i * I_EDGE];
  Wcomb[pk * I_EDGE + t] = acc;
}

// ---------------- Kc2: Wnc[t] = W_node[t] @ cob_node[t]  ([4][128][169]) ----
__global__ __launch_bounds__(192) void k_comb_node(
    const float* __restrict__ Wn, const float* __restrict__ cob,
    float* __restrict__ Wnc) {
  int tf = blockIdx.x;            // t*128 + f
  int ty = tf >> 7;
  int t = threadIdx.x;
  if (t >= I_EDGE) return;
  float acc = 0.f;
  const float* wrow = Wn + tf * I_NODE;
  const float* crow = cob + ty * I_NODE * I_EDGE + t;
  for (int i = 0; i < I_NODE; ++i) acc += wrow[i] * crow[i * I_EDGE];
  Wnc[tf * I_EDGE + t] = acc;
}

// ---------------- K1: m = node_feats @ W_msg ; zero agg ----------------
__global__ __launch_bounds__(128) void k_node_msg(
    const float* __restrict__ nf, const float* __restrict__ Wmsg,
    float* __restrict__ m, float* __restrict__ agg) {
  int n = blockIdx.x, j = threadIdx.x;
  __shared__ float row[FF];
  row[j] = nf[n * FF + j];
  __syncthreads();
  float acc = 0.f;
#pragma unroll 8
  for (int f = 0; f < FF; ++f) acc += row[f] * Wmsg[f * FF + j];
  m[n * FF + j] = acc;
  agg[n * FF + j] = 0.f;
}

// ---------------- K2: symmetric segment sum via atomics ----------------
__global__ __launch_bounds__(256) void k_scatter(
    const float* __restrict__ m, const int* __restrict__ src,
    const int* __restrict__ dst, float* __restrict__ agg) {
  int idx = blockIdx.x * 256 + threadIdx.x;
  if (idx >= EE * FF) return;
  int e = idx >> 7, j = idx & 127;
  int s = src[e], d = dst[e];
  atomicAdd(&agg[d * FF + j], m[s * FF + j]);
  atomicAdd(&agg[s * FF + j], m[d * FF + j]);
}

// ---------------- K3: node_h ----------------
__global__ __launch_bounds__(128) void k_node_h(
    const float* __restrict__ nf, const float* __restrict__ agg,
    const float* __restrict__ na, const float* __restrict__ Wattr,
    float* __restrict__ nh) {
  int n = blockIdx.x, j = threadIdx.x;
  float a = 0.f;
#pragma unroll
  for (int t = 0; t < TT; ++t) a += na[n * TT + t] * Wattr[t * FF + j];
  nh[n * FF + j] = nf[n * FF + j] + agg[n * FF + j] * (1.0f / 20.0f) + a;
}

// ---------------- K4: edge_msg = tanh(e_in @ W_em), 8 edges/block -----------
#define EPB 8
__global__ __launch_bounds__(128) void k_edge_msg(
    const float* __restrict__ nh, const float* __restrict__ ef,
    const float* __restrict__ ea, const int* __restrict__ src,
    const int* __restrict__ dst, const float* __restrict__ Wem,
    float* __restrict__ emsg) {
  int e0 = blockIdx.x * EPB;
  int j = threadIdx.x;
  __shared__ float xin[EPB][2 * FF + 2 * EAA];  // [8][288]
  for (int e = 0; e < EPB; ++e) {
    int ee = e0 + e;
    int s = src[ee], d = dst[ee];
    for (int i = j; i < 288; i += 128) {
      float v;
      if (i < 128)      v = nh[s * FF + i];
      else if (i < 256) v = nh[d * FF + (i - 128)];
      else if (i < 272) v = ef[ee * EAA + (i - 256)];
      else              v = ea[ee * EAA + (i - 272)];
      xin[e][i] = v;
    }
  }
  __syncthreads();
  float acc[EPB];
#pragma unroll
  for (int e = 0; e < EPB; ++e) acc[e] = 0.f;
  for (int c = 0; c < 288; c += 4) {
    float4 xv[EPB];
#pragma unroll
    for (int e = 0; e < EPB; ++e) xv[e] = *(const float4*)&xin[e][c];
#pragma unroll
    for (int sub = 0; sub < 4; ++sub) {
      float w = Wem[(c + sub) * HH + j];
      const float* xs;
#pragma unroll
      for (int e = 0; e < EPB; ++e) {
        float x = (sub == 0) ? xv[e].x : (sub == 1) ? xv[e].y : (sub == 2) ? xv[e].z : xv[e].w;
        acc[e] += x * w;
      }
    }
  }
#pragma unroll
  for (int e = 0; e < EPB; ++e) emsg[(e0 + e) * HH + j] = tanhf(acc[e]);
}

// ---------------- K5: node diagonal blocks (fused basis) ----------------
__global__ __launch_bounds__(192) void k_node_block(
    const float* __restrict__ nh, const int* __restrict__ ntype,
    const float* __restrict__ Wnc, float* __restrict__ M) {
  int n = blockIdx.x, t = threadIdx.x;
  int ty = ntype[n];
  __shared__ float row[FF];
  if (t < FF) row[t] = nh[n * FF + t];
  __syncthreads();
  if (t < I_EDGE) {
    float acc = 0.f;
    const float* W = Wnc + ty * FF * I_EDGE + t;
#pragma unroll 4
    for (int f = 0; f < FF; ++f) acc += row[f] * W[f * I_EDGE];
    int x = t / DD, y = t % DD;
    atomicAdd(&M[(size_t)(n * DD + x) * MROW + (n * DD + y)], acc);
  }
}

// ---------------- K6: edge blocks, fused (h @ Wcomb), 2 edges/block ---------
#define E2 2
__global__ __launch_bounds__(256) void k_edge_blk(
    const float* __restrict__ nh, const float* __restrict__ emsg,
    const int* __restrict__ src, const int* __restrict__ dst,
    const int* __restrict__ etype, const float* __restrict__ Wproj,
    const float* __restrict__ Wcomb, float* __restrict__ M) {
  int e0 = blockIdx.x * E2;
  int t = threadIdx.x;
  __shared__ float xin[E2][384];     // [msg | nh_s | nh_d]
  __shared__ float hp[4][256];       // partials: e0ij, e0ji, e1ij, e1ji
  __shared__ float hv[4][KDIM];
  __shared__ float tji[E2][I_EDGE];
  __shared__ int se[E2], de[E2], pe[E2];

  if (t < E2) {
    int e = e0 + t;
    se[t] = src[e]; de[t] = dst[e]; pe[t] = etype[e];
  }
  __syncthreads();
  for (int e = 0; e < E2; ++e) {
    int ee = e0 + e, s = se[e], d = de[e];
    if (t < 128) {
      xin[e][t] = emsg[ee * HH + t];
      xin[e][256 + t] = nh[d * FF + t];
    } else {
      xin[e][t] = nh[s * FF + (t - 128)];
    }
  }
  __syncthreads();

  // phase A: h = x @ W_proj (384x64). k = t&63, seg = t>>6 covers 96 rows.
  {
    int k = t & 63, seg = t >> 6;
    float a0 = 0.f, a1 = 0.f, a2 = 0.f, a3 = 0.f;
    const float* Wp = Wproj + k;
    int i0 = seg * 96;
    for (int c = i0; c < i0 + 96; c += 4) {
      int cs = (c < 128) ? c : (c < 256 ? c + 128 : c - 128);  // ji swap base
      float4 x0 = *(const float4*)&xin[0][c];
      float4 x0s = *(const float4*)&xin[0][cs];
      float4 x1 = *(const float4*)&xin[1][c];
      float4 x1s = *(const float4*)&xin[1][cs];
      float w0 = Wp[(c + 0) * KDIM], w1 = Wp[(c + 1) * KDIM];
      float w2 = Wp[(c + 2) * KDIM], w3 = Wp[(c + 3) * KDIM];
      a0 += x0.x * w0 + x0.y * w1 + x0.z * w2 + x0.w * w3;
      a1 += x0s.x * w0 + x0s.y * w1 + x0s.z * w2 + x0s.w * w3;
      a2 += x1.x * w0 + x1.y * w1 + x1.z * w2 + x1.w * w3;
      a3 += x1s.x * w0 + x1s.y * w1 + x1s.z * w2 + x1s.w * w3;
    }
    hp[0][t] = a0; hp[1][t] = a1; hp[2][t] = a2; hp[3][t] = a3;
  }
  __syncthreads();
  if (t < KDIM) {
#pragma unroll
    for (int q = 0; q < 4; ++q)
      hv[q][t] = hp[q][t] + hp[q][t + 64] + hp[q][t + 128] + hp[q][t + 192];
  }
  __syncthreads();

  // phase B: blk = h @ Wcomb[p] (64x169); both edges may have different p.
  float b0 = 0.f, b1 = 0.f, b2 = 0.f, b3 = 0.f;
  if (t < I_EDGE) {
    const float* W0 = Wcomb + pe[0] * KDIM * I_EDGE + t;
    const float* W1 = Wcomb + pe[1] * KDIM * I_EDGE + t;
    for (int k = 0; k < KDIM; k += 4) {
      float4 h0 = *(const float4*)&hv[0][k];
      float4 h1 = *(const float4*)&hv[1][k];
      float4 h2 = *(const float4*)&hv[2][k];
      float4 h3 = *(const float4*)&hv[3][k];
      float u0 = W0[(k + 0) * I_EDGE], u1 = W0[(k + 1) * I_EDGE];
      float u2 = W0[(k + 2) * I_EDGE], u3 = W0[(k + 3) * I_EDGE];
      float v0 = W1[(k + 0) * I_EDGE], v1 = W1[(k + 1) * I_EDGE];
      float v2 = W1[(k + 2) * I_EDGE], v3 = W1[(k + 3) * I_EDGE];
      b0 += h0.x * u0 + h0.y * u1 + h0.z * u2 + h0.w * u3;
      b1 += h1.x * u0 + h1.y * u1 + h1.z * u2 + h1.w * u3;
      b2 += h2.x * v0 + h2.y * v1 + h2.z * v2 + h2.w * v3;
      b3 += h3.x * v0 + h3.y * v1 + h3.z * v2 + h3.w * v3;
    }
    tji[0][t] = b1; tji[1][t] = b3;
  }
  __syncthreads();

  if (t < I_EDGE) {
    int x = t / DD, y = t % DD;
    {
      int s = se[0], d = de[0];
      float eb = 0.5f * (b0 + tji[0][y * DD + x]);
      atomicAdd(&M[(size_t)(s * DD + x) * MROW + (d * DD + y)], eb);
      atomicAdd(&M[(size_t)(d * DD + y) * MROW + (s * DD + x)], eb);
    }
    {
      int s = se[1], d = de[1];
      float eb = 0.5f * (b2 + tji[1][y * DD + x]);
      atomicAdd(&M[(size_t)(s * DD + x) * MROW + (d * DD + y)], eb);
      atomicAdd(&M[(size_t)(d * DD + y) * MROW + (s * DD + x)], eb);
    }
  }
}

extern "C" void kernel_launch(void* const* d_in, const int* in_sizes, int n_in,
                              void* d_out, int out_size, void* d_ws, size_t ws_size,
                              hipStream_t stream) {
  const float* node_feats = (const float*)d_in[0];
  const float* node_attrs = (const float*)d_in[1];
  const float* edge_feats = (const float*)d_in[2];
  const float* edge_attrs = (const float*)d_in[3];
  const int*   edge_index = (const int*)d_in[4];
  const int*   node_types = (const int*)d_in[5];
  const int*   edge_types = (const int*)d_in[6];
  const float* W_msg  = (const float*)d_in[7];
  const float* W_attr = (const float*)d_in[8];
  const float* W_em   = (const float*)d_in[9];
  const float* W_proj = (const float*)d_in[10];
  const float* W_node = (const float*)d_in[11];
  const float* W_edge = (const float*)d_in[12];
  const float* cob_node = (const float*)d_in[13];
  const float* cob_edge = (const float*)d_in[14];

  float* M  = (float*)d_out;
  float* ws = (float*)d_ws;
  float* m_buf = ws;                  // N*F = 128000
  float* agg   = ws + 128000;         // N*F
  float* nh    = ws + 256000;         // N*F
  float* emsg  = ws + 384000;         // E*H = 2,560,000
  float* Wcomb = ws + 2944000;        // P*K*I_EDGE = 108,160
  float* Wnc   = ws + 3052160;        // T*F*I_EDGE = 86,528  (total ~12.6 MB)

  const int* src = edge_index;        // edge_index[0]
  const int* dst = edge_index + EE;   // edge_index[1]

  long n4 = (long)out_size / 4;
  k_zero      <<<(int)((n4 + 255) / 256), 256, 0, stream>>>((float4*)M, n4);
  k_comb_edge <<<PP * KDIM, 192, 0, stream>>>(W_edge, cob_edge, Wcomb);
  k_comb_node <<<TT * FF, 192, 0, stream>>>(W_node, cob_node, Wnc);
  k_node_msg  <<<NN, 128, 0, stream>>>(node_feats, W_msg, m_buf, agg);
  k_scatter   <<<(EE * FF) / 256, 256, 0, stream>>>(m_buf, src, dst, agg);
  k_node_h    <<<NN, 128, 0, stream>>>(node_feats, agg, node_attrs, W_attr, nh);
  k_edge_msg  <<<EE / EPB, 128, 0, stream>>>(nh, edge_feats, edge_attrs, src, dst, W_em, emsg);
  k_node_block<<<NN, 192, 0, stream>>>(nh, node_types, Wnc, M);
  k_edge_blk  <<<EE / E2, 256, 0, stream>>>(nh, emsg, src, dst, edge_types,
                                            W_proj, Wcomb, M);
}